// Round 10
// baseline (115.854 us; speedup 1.0000x reference)
//
#include <hip/hip_runtime.h>
#include <hip/hip_bf16.h>

#define B_ROWS 8192
#define C_IN   4096
#define G_GRP  8
#define CG     512
#define J_RANK 512

// ---- GEMM geometry: 128x256 tile, BK=32, 8 waves (2x4), wave tile 64x64 ----
#define BM 128
#define BN 256
#define BK 32
#define NKT (CG / BK)                 // 16 K-tiles

// ---- permute geometry: wave-private slices, zero barriers ----
#define PW_WAVES 8
#define PW_RPW   4                                  // rows per wave
#define PW_BLOCKS (B_ROWS / (PW_WAVES * PW_RPW))    // 256

typedef __attribute__((ext_vector_type(8))) short bf16x8;
typedef __attribute__((ext_vector_type(4))) float f32x4;
typedef __attribute__((ext_vector_type(8))) unsigned short u16x8;

struct ushort4v { unsigned short x, y, z, w; };

__device__ __forceinline__ unsigned short f2bf(float f) {
    unsigned int u = __float_as_uint(f);
    unsigned int r = (u + 0x7FFFu + ((u >> 16) & 1u)) >> 16;  // RNE
    return (unsigned short)r;
}

// ---------------- kernel 1: convert weights fp32 -> bf16 ----------------
__global__ __launch_bounds__(256) void convert_w_kernel(
    const float* __restrict__ w, unsigned short* __restrict__ wb, int n4) {
    int i = blockIdx.x * 256 + threadIdx.x;
    if (i >= n4) return;
    float4 v = ((const float4*)w)[i];
    ushort4v o;
    o.x = f2bf(v.x); o.y = f2bf(v.y); o.z = f2bf(v.z); o.w = f2bf(v.w);
    ((ushort4v*)wb)[i] = o;
}

// -------- kernel 2: gather-permute x, wave-private LDS, ZERO barriers ---
// 256 blocks x 8 waves; each wave owns a 16KB LDS slice and processes 4
// rows depth-1: stage own row (16 x global_load_lds 16B), per-wave
// s_waitcnt vmcnt(0) (no s_barrier anywhere), 64 LDS gathers/lane,
// 8 coalesced 16B stores. Latency hidden by the co-SIMD wave (2 waves/SIMD)
// + 8 concurrent row-DMAs per CU. R6's block-shared buffer forced 2
// barriers/row across 4 waves -- that serialization was the 47us cost.
__global__ __launch_bounds__(512, 2) void permute_x_kernel(
    const float* __restrict__ x, const int* __restrict__ arr,
    unsigned short* __restrict__ xp) {
    __shared__ float slice_all[PW_WAVES][C_IN];   // 8 x 16 KB = 128 KB
    const int tid = threadIdx.x;
    const int w   = tid >> 6;
    const int l   = tid & 63;
    float* slice = &slice_all[w][0];
    const int row0 = blockIdx.x * (PW_WAVES * PW_RPW) + w * PW_RPW;

    // arrangements declared int64 in the reference; harness may hand int32.
    // int64 little-endian => odd int32 words all 0 (values < 4096).
    const bool is64 = (arr[1] == 0 && arr[3] == 0 && arr[5] == 0 && arr[7] == 0);

    // lane l owns output positions c*512 + l*8 + j (c=0..7, j=0..7)
    int sidx[64];
#pragma unroll
    for (int c = 0; c < 8; ++c)
#pragma unroll
        for (int j = 0; j < 8; ++j) {
            int p = c * 512 + l * 8 + j;
            sidx[c * 8 + j] = is64 ? arr[2 * p] : arr[p];
        }

#pragma unroll
    for (int r = 0; r < PW_RPW; ++r) {
        const float* xrow = x + (size_t)(row0 + r) * C_IN;
        // stage own row: 16 instrs x (64 lanes x 16B) = 16 KB
#pragma unroll
        for (int i = 0; i < 16; ++i) {
            __builtin_amdgcn_global_load_lds(
                (const __attribute__((address_space(1))) unsigned int*)
                    (xrow + i * 256 + l * 4),
                (__attribute__((address_space(3))) unsigned int*)
                    (slice + i * 256 + l * 4),
                16, 0, 0);
        }
        asm volatile("s_waitcnt vmcnt(0)" ::: "memory");   // per-wave; no barrier
        __builtin_amdgcn_sched_barrier(0);

        unsigned short* orow = xp + (size_t)(row0 + r) * C_IN;
#pragma unroll
        for (int c = 0; c < 8; ++c) {
            u16x8 o;
#pragma unroll
            for (int j = 0; j < 8; ++j)
                o[j] = f2bf(slice[sidx[c * 8 + j]]);
            *(u16x8*)(orow + c * 512 + l * 8) = o;
        }
        // drain this wave's ds_reads before the DMA of the next row
        // overwrites the slice (stores don't touch LDS; reads are in regs).
        asm volatile("s_waitcnt lgkmcnt(0)" ::: "memory");
        __builtin_amdgcn_sched_barrier(0);
    }
}

// -------- kernel 3: grouped GEMM, 128x256/BK32, 2-phase, 2 blocks/CU ----
// (unchanged from R9 -- best so far)
__global__ __launch_bounds__(512, 4) void gemm_kernel(
    const unsigned short* __restrict__ Xp,   // [B][4096] bf16 (permuted)
    const unsigned short* __restrict__ Wb,   // [G][J][CG] bf16
    const float* __restrict__ bias,          // [G][J]
    float* __restrict__ out) {               // [B][4096] fp32
    __shared__ unsigned short ldsA[3][BM * BK];   // 3 x 8 KB
    __shared__ unsigned short ldsB[2][BN * BK];   // 2 x 16 KB

    const int tid = threadIdx.x;
    const int g   = blockIdx.x & 7;
    const int idx = blockIdx.x >> 3;   // 0..127
    const int mt  = idx >> 1;          // 0..63
    const int nt  = idx & 1;

    const int l   = tid & 63;
    const int wv  = tid >> 6;          // 0..7
    const int wr  = wv >> 2;           // 0..1  (M half: rows wr*64..+63)
    const int wc  = wv & 3;            // 0..3  (N quarter: cols wc*64..+63)
    const int lr  = l & 15;
    const int lkq = l >> 4;            // 0..3

    const unsigned short* Ab = Xp + (size_t)(mt * BM) * C_IN + g * CG;
    const unsigned short* Bb = Wb + (size_t)g * J_RANK * CG + (size_t)(nt * BN) * CG;

    f32x4 acc[4][4];
#pragma unroll
    for (int m = 0; m < 4; ++m)
#pragma unroll
        for (int n = 0; n < 4; ++n) acc[m][n] = (f32x4){0.f, 0.f, 0.f, 0.f};

    // read offset within a row: chunk lkq, swizzled by row bits 2-3 (=lr>>2)
    const int coff = (lkq ^ ((lr >> 2) & 3)) * 8;

#define STAGE_A(kt_)                                                          \
    do { const int p_ = (kt_) % 3;                                            \
        int c_ = tid;                                                         \
        int rl_ = c_ >> 2, gc_ = (c_ & 3) ^ ((rl_ >> 2) & 3);                 \
        __builtin_amdgcn_global_load_lds(                                     \
            (const __attribute__((address_space(1))) unsigned int*)           \
                (Ab + (size_t)rl_ * C_IN + (kt_) * BK + gc_ * 8),             \
            (__attribute__((address_space(3))) unsigned int*)                 \
                (&ldsA[p_][0] + c_ * 8),                                      \
            16, 0, 0);                                                        \
    } while (0)

#define STAGE_B(kt_)                                                          \
    do { const int p_ = (kt_) & 1;                                            \
        _Pragma("unroll")                                                     \
        for (int i_ = 0; i_ < 2; ++i_) {                                      \
            int c_ = i_ * 512 + tid;                                          \
            int rl_ = c_ >> 2, gc_ = (c_ & 3) ^ ((rl_ >> 2) & 3);             \
            __builtin_amdgcn_global_load_lds(                                 \
                (const __attribute__((address_space(1))) unsigned int*)       \
                    (Bb + (size_t)rl_ * CG + (kt_) * BK + gc_ * 8),           \
                (__attribute__((address_space(3))) unsigned int*)             \
                    (&ldsB[p_][0] + c_ * 8),                                  \
                16, 0, 0);                                                    \
        }                                                                     \
    } while (0)

#define LDA(m_) (*(const bf16x8*)&ldsA[bufA][(wr * 64 + (m_) * 16 + lr) * BK + coff])
#define LDB(n_) (*(const bf16x8*)&ldsB[bufB][(wc * 64 + (n_) * 16 + lr) * BK + coff])

#define PHASE_TAIL()                                                          \
    __builtin_amdgcn_s_barrier();                                             \
    asm volatile("s_waitcnt lgkmcnt(0)" ::: "memory");                        \
    __builtin_amdgcn_sched_barrier(0);                                        \
    __builtin_amdgcn_s_setprio(1)

#define PHASE_END()                                                           \
    __builtin_amdgcn_s_setprio(0);                                            \
    __builtin_amdgcn_s_barrier()

    // ---- prologue: stage kt0, kt1 (3 instrs each); wait kt0 landed ----
    STAGE_A(0); STAGE_B(0);
    STAGE_A(1); STAGE_B(1);
    asm volatile("s_waitcnt vmcnt(3)" ::: "memory");
    __builtin_amdgcn_s_barrier();

    bf16x8 bfr[4], af[2];

    for (int kt = 0; kt < NKT; ++kt) {
        const int bufA = kt % 3;
        const int bufB = kt & 1;

        // ---- phase 0: read B(all 4) + A(m0,m1); stage A(kt+2) ----
#pragma unroll
        for (int n = 0; n < 4; ++n) bfr[n] = LDB(n);
        af[0] = LDA(0); af[1] = LDA(1);
        if (kt + 2 < NKT) STAGE_A(kt + 2);
        PHASE_TAIL();
#pragma unroll
        for (int mm = 0; mm < 2; ++mm)
#pragma unroll
            for (int n = 0; n < 4; ++n)
                acc[mm][n] = __builtin_amdgcn_mfma_f32_16x16x32_bf16(
                    af[mm], bfr[n], acc[mm][n], 0, 0, 0);
        PHASE_END();

        // ---- phase 1: read A(m2,m3); stage B(kt+2); counted vmcnt ----
        af[0] = LDA(2); af[1] = LDA(3);
        if (kt + 2 < NKT) STAGE_B(kt + 2);
        if (kt <= NKT - 3)      asm volatile("s_waitcnt vmcnt(3)" ::: "memory");
        else if (kt == NKT - 2) asm volatile("s_waitcnt vmcnt(0)" ::: "memory");
        PHASE_TAIL();
#pragma unroll
        for (int mm = 0; mm < 2; ++mm)
#pragma unroll
            for (int n = 0; n < 4; ++n)
                acc[2 + mm][n] = __builtin_amdgcn_mfma_f32_16x16x32_bf16(
                    af[mm], bfr[n], acc[2 + mm][n], 0, 0, 0);
        PHASE_END();
    }
#undef STAGE_A
#undef STAGE_B
#undef LDA
#undef LDB
#undef PHASE_TAIL
#undef PHASE_END

    // epilogue: D frag layout col = lane&15, row = (lane>>4)*4 + r
    const int r0 = mt * BM + wr * 64 + (lkq << 2);
    const int cbase = nt * BN + wc * 64 + lr;   // within group's 512 cols
#pragma unroll
    for (int n = 0; n < 4; ++n) {
        int col = cbase + n * 16;
        float bv = bias[g * J_RANK + col];
#pragma unroll
        for (int m = 0; m < 4; ++m) {
            int row = r0 + m * 16;
            float* op = out + (size_t)row * C_IN + g * J_RANK + col;
#pragma unroll
            for (int r = 0; r < 4; ++r)
                op[(size_t)r * C_IN] = acc[m][n][r] + bv;
        }
    }
}

extern "C" void kernel_launch(void* const* d_in, const int* in_sizes, int n_in,
                              void* d_out, int out_size, void* d_ws, size_t ws_size,
                              hipStream_t stream) {
    const float* x    = (const float*)d_in[0];
    const int*   arr  = (const int*)d_in[1];
    const float* w    = (const float*)d_in[2];
    const float* bias = (const float*)d_in[3];
    float* out = (float*)d_out;

    // workspace: xp bf16 [8192][4096] (64MB) | wb bf16 [8][512][512] (4MB)
    unsigned short* xp = (unsigned short*)d_ws;
    unsigned short* wb = xp + (size_t)B_ROWS * C_IN;

    hipLaunchKernelGGL(convert_w_kernel, dim3((G_GRP * J_RANK * CG / 4 + 255) / 256),
                       dim3(256), 0, stream, w, wb, G_GRP * J_RANK * CG / 4);
    hipLaunchKernelGGL(permute_x_kernel, dim3(PW_BLOCKS), dim3(512), 0, stream,
                       x, arr, xp);
    hipLaunchKernelGGL(gemm_kernel,
                       dim3(G_GRP * (B_ROWS / BM) * (J_RANK / BN)), dim3(512),
                       0, stream, xp, wb, bias, out);
}